// Round 20
// baseline (189.143 us; speedup 1.0000x reference)
//
#include <hip/hip_runtime.h>
#include <hip/hip_bf16.h>

#define NTOK 8192
#define DIN  1024
#define HID  2048
#define OUTD 1024
#define NEXP 8
#define BM 128
#define MAXT (NTOK / BM + NEXP)   // 72 M-tiles max

#define T1BLK 1024                // W1 transpose blocks (4 tiles each): 4096/4
#define RTBLK 512                 // router blocks (4 groups each): 2048/4
#define T2BLK 4096                // W2 transpose blocks (1 tile each)
#define G1BLK ((HID / 128) * MAXT)   // 1152 GEMM1 blocks (div by 8)

typedef short short8 __attribute__((ext_vector_type(8)));
typedef float f32x4 __attribute__((ext_vector_type(4)));

static __device__ __forceinline__ unsigned short f2bf(float f) {
  union { __hip_bfloat16 b; unsigned short u; } cv;
  cv.b = __float2bfloat16(f);
  return cv.u;
}

static __device__ __forceinline__ void gload_lds16(const void* g, void* l) {
  __builtin_amdgcn_global_load_lds(
      (const __attribute__((address_space(1))) void*)g,
      (__attribute__((address_space(3))) void*)l, 16, 0, 0);
}

// ---------------- transpose tile: W [E][R][C] fp32 -> WT [E][C][R] bf16 -----
static __device__ void transpose_tile(const float* __restrict__ W,
                                      unsigned short* __restrict__ WT,
                                      int R, int C, int bx, int by, int e,
                                      float* smemf) {
  float (*tile)[65] = (float(*)[65])smemf;
  const int c0 = bx * 64, r0 = by * 64;
  const int lr = threadIdx.x >> 4;    // 0..15
  const int fc = threadIdx.x & 15;    // float4 column
  const float* Wp = W + ((size_t)e * R + r0) * C + c0;
#pragma unroll
  for (int i = 0; i < 4; ++i) {
    int r = lr + i * 16;
    float4 v = *(const float4*)(Wp + (size_t)r * C + fc * 4);
    tile[r][fc * 4 + 0] = v.x; tile[r][fc * 4 + 1] = v.y;
    tile[r][fc * 4 + 2] = v.z; tile[r][fc * 4 + 3] = v.w;
  }
  __syncthreads();
  unsigned short* Op = WT + ((size_t)e * C + c0) * R + r0;
  const int cc0 = threadIdx.x >> 3;   // 0..31
  const int rc = threadIdx.x & 7;     // 8-row source chunk
#pragma unroll
  for (int i = 0; i < 2; ++i) {
    int cc = cc0 + i * 32;
    short8 o;
#pragma unroll
    for (int j = 0; j < 8; ++j) o[j] = (short)f2bf(tile[rc * 8 + j][cc]);
    *(short8*)(Op + (size_t)cc * R + rc * 8) = o;   // 16B/lane, coalesced
  }
}

// 4 tiles per block (amortizes launch/fixed cost); barrier guards LDS reuse.
static __device__ void transpose_quad(const float* __restrict__ W,
                                      unsigned short* __restrict__ WT,
                                      int R, int C, int xtiles, int b,
                                      float* smemf) {
  for (int i = 0; i < 4; ++i) {
    if (i) __syncthreads();            // prev tile's LDS reads done
    int t = b * 4 + i;
    int e = t >> 9, rem = t & 511;
    transpose_tile(W, WT, R, C, rem & (xtiles - 1), rem / xtiles, e, smemf);
  }
}

// ---------------- router: x fp32 -> xb bf16 + probs + routes ----------------
// Stages WrL ONCE, then processes 4 token-groups (16 tokens) per block.
static __device__ void router_body4(const float* __restrict__ x,
                                    const float* __restrict__ Wr,
                                    const float* __restrict__ br,
                                    unsigned short* __restrict__ xb,
                                    float* __restrict__ probs_out,
                                    int* __restrict__ routes,
                                    int blk, float* smemf) {
  float (*WrL)[DIN] = (float(*)[DIN])smemf;   // [NEXP][DIN] = 32 KB
  const int tid = threadIdx.x;
  {
    const int r0 = tid * 4;
    float wlo[4][4], whi[4][4];
#pragma unroll
    for (int rr = 0; rr < 4; ++rr) {
      float4 v0 = *(const float4*)(Wr + (size_t)(r0 + rr) * NEXP);
      float4 v1 = *(const float4*)(Wr + (size_t)(r0 + rr) * NEXP + 4);
      wlo[rr][0] = v0.x; wlo[rr][1] = v0.y; wlo[rr][2] = v0.z; wlo[rr][3] = v0.w;
      whi[rr][0] = v1.x; whi[rr][1] = v1.y; whi[rr][2] = v1.z; whi[rr][3] = v1.w;
    }
#pragma unroll
    for (int e = 0; e < 4; ++e) {
      float4 o = { wlo[0][e], wlo[1][e], wlo[2][e], wlo[3][e] };
      *(float4*)&WrL[e][r0] = o;                 // lane stride 16B: no conflict
      float4 o2 = { whi[0][e], whi[1][e], whi[2][e], whi[3][e] };
      *(float4*)&WrL[e + 4][r0] = o2;
    }
  }
  __syncthreads();

  const int lane = tid & 63;
  for (int g = 0; g < 4; ++g) {
    const int n = blk * 16 + g * 4 + (tid >> 6);
    const float4* xr = (const float4*)(x + (size_t)n * DIN);
    ushort4* xo = (ushort4*)(xb + (size_t)n * DIN);
    float acc[NEXP];
#pragma unroll
    for (int e = 0; e < NEXP; ++e) acc[e] = 0.f;
#pragma unroll
    for (int j = 0; j < 4; ++j) {
      int idx = j * 64 + lane;          // coalesced: 64 consecutive float4
      float4 xv = xr[idx];
      ushort4 o = { f2bf(xv.x), f2bf(xv.y), f2bf(xv.z), f2bf(xv.w) };
      xo[idx] = o;
      int r0 = idx * 4;
#pragma unroll
      for (int e = 0; e < NEXP; ++e) {
        float4 wv = *(const float4*)&WrL[e][r0];
        acc[e] += xv.x * wv.x + xv.y * wv.y + xv.z * wv.z + xv.w * wv.w;
      }
    }
#pragma unroll
    for (int m = 1; m < 64; m <<= 1)
#pragma unroll
      for (int e = 0; e < NEXP; ++e) acc[e] += __shfl_xor(acc[e], m);

    if (lane == 0) {
      float lg[NEXP], p[NEXP];
      float mx = -1e30f;
#pragma unroll
      for (int e = 0; e < NEXP; ++e) { lg[e] = acc[e] + br[e]; mx = fmaxf(mx, lg[e]); }
      float s = 0.f;
#pragma unroll
      for (int e = 0; e < NEXP; ++e) { p[e] = expf(lg[e] - mx); s += p[e]; }
      float inv = 1.f / s;
      int best = 0; float bp = -1.f;
#pragma unroll
      for (int e = 0; e < NEXP; ++e) {
        p[e] *= inv;
        probs_out[(size_t)n * NEXP + e] = p[e];
        if (p[e] > bp) { bp = p[e]; best = e; }   // strict > tie-break
      }
      routes[n] = best;
    }
  }
}

// ============ prep1: W1-transpose | router (critical path for GEMM1) =======
__global__ __launch_bounds__(256) void prep1_kernel(
    const float* __restrict__ W1, unsigned short* __restrict__ w1t,
    const float* __restrict__ x, const float* __restrict__ Wr,
    const float* __restrict__ br, unsigned short* __restrict__ xb,
    float* __restrict__ probs_out, int* __restrict__ routes) {
  __shared__ float smemf[8192];   // 32 KB union
  const int bid = blockIdx.x;
  if (bid < T1BLK) {
    transpose_quad(W1, w1t, DIN, HID, 32, bid, smemf);  // W1: 32 x-tiles
  } else {
    router_body4(x, Wr, br, xb, probs_out, routes, bid - T1BLK, smemf);
  }
}

// ====== fused hist + scan + build + pad-fill (ONE single-block kernel) ======
__global__ __launch_bounds__(256) void hist_build_kernel(
    const int* __restrict__ routes, int* __restrict__ pad_off,
    int2* __restrict__ tile_table, float* __restrict__ counts_out,
    int* __restrict__ sorted) {
  __shared__ int rloc[NTOK];          // 32 KB
  __shared__ int cpre[256][NEXP];     // 8 KB
  __shared__ int tot[NEXP], pstart[NEXP], pend[NEXP];
  const int tid = threadIdx.x;
#pragma unroll
  for (int j = 0; j < 8; ++j)
    ((int4*)rloc)[tid + 256 * j] = ((const int4*)routes)[tid + 256 * j];
  __syncthreads();

  const int t0 = tid * 32;
  int cnt[NEXP];
#pragma unroll
  for (int e = 0; e < NEXP; ++e) cnt[e] = 0;
  for (int i = 0; i < 32; ++i) {
    int r = rloc[t0 + i];
#pragma unroll
    for (int e = 0; e < NEXP; ++e) cnt[e] += (r == e);
  }
#pragma unroll
  for (int e = 0; e < NEXP; ++e) cpre[tid][e] = cnt[e];
  __syncthreads();
  if (tid < NEXP) {                    // 8 threads: serial exclusive prefix
    int run = 0;
    for (int i = 0; i < 256; ++i) { int c = cpre[i][tid]; cpre[i][tid] = run; run += c; }
    tot[tid] = run;
  }
  __syncthreads();
  if (tid == 0) {
    int off = 0, t = 0;
    for (int e = 0; e < NEXP; ++e) {
      int c = tot[e];
      pad_off[e] = off;
      counts_out[e] = (float)c;
      int tiles = (c + BM - 1) / BM;
      pstart[e] = off + c;
      pend[e] = off + tiles * BM;
      for (int i = 0; i < tiles; ++i) { tile_table[t] = make_int2(e, off + i * BM); ++t; }
      off += tiles * BM;
    }
    for (; t < MAXT; ++t) tile_table[t] = make_int2(-1, 0);
  }
  __syncthreads();
  int pos[NEXP];
#pragma unroll
  for (int e = 0; e < NEXP; ++e) pos[e] = pad_off[e] + cpre[tid][e];
  for (int i = 0; i < 32; ++i) {
    int r = rloc[t0 + i];
#pragma unroll
    for (int e = 0; e < NEXP; ++e)     // compile-time index: pos stays in regs
      if (r == e) { sorted[pos[e]] = t0 + i; ++pos[e]; }
  }
#pragma unroll
  for (int e = 0; e < NEXP; ++e)
    for (int i = pstart[e] + tid; i < pend[e]; i += 256) sorted[i] = -1;
}

// ===== grouped GEMM body: m97 structure, VGPR-dieted for 4 blocks/CU ========
// 128x128 tile, BK=64, 4 waves, single-buffered 32KB LDS, two barriers/step.
// VGPR diet vs R19 (true use ~148 -> ~125): (1) K-step split into two
// k-halves reusing ONE set of 8 frag regs (64->32); (2) srcB collapsed to a
// single base + compile-time i*32*KDIM; (3) LDS dst = tid*8 + folded consts;
// (4) k=1 ds_read offset = k0 ^ 32 shorts (XOR, not add: the row-swizzle bit
// rsw<<4 overlaps the k bit at byte 64 -- both-sides consistent, rule #21).
// launch_bounds(256,4): 4 blocks/CU, 16 waves. SPILL CHECK: if FETCH_SIZE
// balloons (R17 signature: acc in scratch), revert to (256,3).
// Swizzle (G4): chunk ^= row&7 on pre-swizzled gload source AND
// byte ^= (fr&7)<<4 on ds_read.
// MODE 0: A = xb gathered, out = relu(acc+b1) -> bf16 hbuf[token][NDIM]
// MODE 1: A = hbuf gathered, out = acc+b2     -> fp32 out[token][NDIM]
template <int KDIM, int MODE, int NB>
static __device__ void gemm_body(
    short* lds, int bid,
    const unsigned short* __restrict__ A, const unsigned short* __restrict__ WT,
    const float* __restrict__ bias, const int* __restrict__ sorted,
    const int2* __restrict__ tile_table, void* __restrict__ Cout, int NDIM) {
  // T1 bijective XCD swizzle (nwg % 8 == 0)
  const int nwg = NB * MAXT;
  const int swz = (bid & 7) * (nwg >> 3) + (bid >> 3);
  const int2 tt = tile_table[swz / NB];
  if (tt.x < 0) return;
  const int expert = tt.x, mbase = tt.y;
  const int n0 = (swz % NB) * 128;
  const int tid = threadIdx.x, lane = tid & 63, w = tid >> 6;
  const int qm = w >> 1, qn = w & 1;
  const int fr = lane & 15, klo = lane >> 4;

  // ---- staging: chunk i covers row i*32 + (tid>>3); (ch&7, row&7) const in i
  const int row0 = tid >> 3;
  const int csw = ((tid & 7) ^ (row0 & 7)) * 8;       // inverse-swizzled source
  const int dst0 = tid * 8;                           // linear LDS dest (shorts)
  const short* srcA[4];
#pragma unroll
  for (int i = 0; i < 4; ++i) {
    int tok = sorted[mbase + i * 32 + row0];
    if (tok < 0) tok = 0;                             // pad: dropped at store
    srcA[i] = (const short*)A + (size_t)tok * KDIM + csw;
  }
  const short* srcB0 = (const short*)WT +
      ((size_t)expert * NDIM + n0 + row0) * KDIM + csw;

  // ---- fragment ds_read offsets, k=0 half (shorts); k=1 = ^32
  const int rsw = (fr & 7) << 4;            // row&7 == fr&7 (bases are x16)
  int aoff[4], boff[4];
#pragma unroll
  for (int i = 0; i < 4; ++i) {
    int ba = (qm * 64 + i * 16 + fr) * 128 + klo * 16;
    aoff[i] = (ba ^ rsw) >> 1;
    int bb = (qn * 64 + i * 16 + fr) * 128 + klo * 16;
    boff[i] = ((bb ^ rsw) >> 1) + 8192;
  }

  f32x4 acc[4][4];
#pragma unroll
  for (int mi = 0; mi < 4; ++mi)
#pragma unroll
    for (int nj = 0; nj < 4; ++nj) acc[mi][nj] = (f32x4){0.f, 0.f, 0.f, 0.f};

  constexpr int NKT = KDIM / 64;
  for (int t = 0; t < NKT; ++t) {
    if (t) __syncthreads();               // prev tile's reads done
    const int ko = t * 64;
#pragma unroll
    for (int i = 0; i < 4; ++i) {
      gload_lds16(srcA[i] + ko, &lds[dst0 + i * 2048]);
      gload_lds16(srcB0 + (size_t)i * 32 * KDIM + ko, &lds[8192 + dst0 + i * 2048]);
    }
    __syncthreads();                      // compiler drains vmcnt(0): tile ready
    short8 a[4], b[4];                    // ONE frag set, reused per k-half
#pragma unroll
    for (int i = 0; i < 4; ++i) {
      a[i] = *(const short8*)&lds[aoff[i]];
      b[i] = *(const short8*)&lds[boff[i]];
    }
    __builtin_amdgcn_s_setprio(1);
#pragma unroll
    for (int mi = 0; mi < 4; ++mi)
#pragma unroll
      for (int nj = 0; nj < 4; ++nj)
        acc[mi][nj] = __builtin_amdgcn_mfma_f32_16x16x32_bf16(
            a[mi], b[nj], acc[mi][nj], 0, 0, 0);
    __builtin_amdgcn_s_setprio(0);
#pragma unroll
    for (int i = 0; i < 4; ++i) {         // k=1 half: offset ^32 shorts
      a[i] = *(const short8*)&lds[aoff[i] ^ 32];
      b[i] = *(const short8*)&lds[boff[i] ^ 32];
    }
    __builtin_amdgcn_s_setprio(1);
#pragma unroll
    for (int mi = 0; mi < 4; ++mi)
#pragma unroll
      for (int nj = 0; nj < 4; ++nj)
        acc[mi][nj] = __builtin_amdgcn_mfma_f32_16x16x32_bf16(
            a[mi], b[nj], acc[mi][nj], 0, 0, 0);
    __builtin_amdgcn_s_setprio(0);
  }

  // ---- epilogue: scatter rows to token-indexed buffer ----
  const int fq = lane >> 4;
#pragma unroll
  for (int mi = 0; mi < 4; ++mi) {
    const int rbase = mbase + qm * 64 + mi * 16 + fq * 4;
    int tok[4];
#pragma unroll
    for (int r = 0; r < 4; ++r) tok[r] = sorted[rbase + r];
#pragma unroll
    for (int nj = 0; nj < 4; ++nj) {
      const int col = n0 + qn * 64 + nj * 16 + fr;
      const float bv = bias[(size_t)expert * NDIM + col];
#pragma unroll
      for (int r = 0; r < 4; ++r) {
        if (tok[r] < 0) continue;           // pad row
        float v = acc[mi][nj][r] + bv;
        if (MODE == 0) {
          ((unsigned short*)Cout)[(size_t)tok[r] * NDIM + col] = f2bf(fmaxf(v, 0.f));
        } else {
          ((float*)Cout)[(size_t)tok[r] * NDIM + col] = v;
        }
      }
    }
  }
}

// ===== kernel B: GEMM1 blocks first, then W2-transpose blocks (single-tile) =
__global__ __launch_bounds__(256, 4) void gemm1_t2_kernel(
    const unsigned short* __restrict__ xb, const unsigned short* __restrict__ w1t,
    const float* __restrict__ b1, const int* __restrict__ sorted,
    const int2* __restrict__ tile_table, unsigned short* __restrict__ hbuf,
    const float* __restrict__ W2, unsigned short* __restrict__ w2t) {
  __shared__ short lds[16384];   // 32 KB
  const int bid = blockIdx.x;
  if (bid < G1BLK) {
    gemm_body<DIN, 0, HID / 128>(lds, bid, xb, w1t, b1, sorted, tile_table,
                                 (void*)hbuf, HID);
  } else {
    int b = bid - G1BLK;          // W2: R=HID(32 tiles), C=OUTD(16 tiles)
    int e = b >> 9, rem = b & 511;
    transpose_tile(W2, w2t, HID, OUTD, rem & 15, rem >> 4, e, (float*)lds);
  }
}

template <int KDIM, int MODE, int NB>
__global__ __launch_bounds__(256, 4) void gemm_moe(
    const unsigned short* __restrict__ A, const unsigned short* __restrict__ WT,
    const float* __restrict__ bias, const int* __restrict__ sorted,
    const int2* __restrict__ tile_table, void* __restrict__ Cout, int NDIM) {
  __shared__ short lds[16384];   // 32 KB
  gemm_body<KDIM, MODE, NB>(lds, blockIdx.x, A, WT, bias, sorted, tile_table,
                            Cout, NDIM);
}

extern "C" void kernel_launch(void* const* d_in, const int* in_sizes, int n_in,
                              void* d_out, int out_size, void* d_ws, size_t ws_size,
                              hipStream_t stream) {
  const float* x  = (const float*)d_in[0];
  const float* Wr = (const float*)d_in[1];
  const float* br = (const float*)d_in[2];
  const float* W1 = (const float*)d_in[3];
  const float* b1 = (const float*)d_in[4];
  const float* W2 = (const float*)d_in[5];
  const float* b2 = (const float*)d_in[6];

  float* out_y      = (float*)d_out;                      // [N,O]
  float* out_probs  = out_y + (size_t)NTOK * OUTD;        // [N,E]
  float* out_counts = out_probs + (size_t)NTOK * NEXP;    // [E]

  char* ws = (char*)d_ws;
  unsigned short* xb   = (unsigned short*)(ws);                                  // 16 MB
  unsigned short* w1t  = (unsigned short*)(ws + 16777216ULL);                    // 32 MB
  unsigned short* w2t  = (unsigned short*)(ws + 50331648ULL);                    // 32 MB
  unsigned short* hbuf = (unsigned short*)(ws + 83886080ULL);                    // 32 MB (token-indexed)
  char* p = ws + 117440512ULL;
  int* routes   = (int*)p; p += 32768;
  int* sorted   = (int*)p; p += (NTOK + NEXP * BM) * 4;
  int* pad_off  = (int*)p; p += 256;
  int2* tt      = (int2*)p;

  prep1_kernel<<<T1BLK + RTBLK, 256, 0, stream>>>(
      W1, w1t, x, Wr, br, xb, out_probs, routes);
  hist_build_kernel<<<1, 256, 0, stream>>>(routes, pad_off, tt, out_counts,
                                           sorted);
  gemm1_t2_kernel<<<G1BLK + T2BLK, 256, 0, stream>>>(
      xb, w1t, b1, sorted, tt, hbuf, W2, w2t);
  gemm_moe<HID, 1, OUTD / 128><<<(OUTD / 128) * MAXT, 256, 0, stream>>>(
      hbuf, w2t, b2, sorted, tt, out_y, OUTD);
}

// Round 21
// 164.738 us; speedup vs baseline: 1.1481x; 1.1481x over previous
//
#include <hip/hip_runtime.h>
#include <hip/hip_bf16.h>

#define NTOK 8192
#define DIN  1024
#define HID  2048
#define OUTD 1024
#define NEXP 8
#define BM 128
#define MAXT (NTOK / BM + NEXP)   // 72 M-tiles max

#define T1BLK 1024                // W1 transpose blocks (4 tiles each): 4096/4
#define RTBLK 512                 // router blocks (4 groups each): 2048/4
#define T2BLK 4096                // W2 transpose blocks (1 tile each)
#define G1BLK ((HID / 128) * MAXT)   // 1152 GEMM1 blocks (div by 8)

typedef short short8 __attribute__((ext_vector_type(8)));
typedef float f32x4 __attribute__((ext_vector_type(4)));

static __device__ __forceinline__ unsigned short f2bf(float f) {
  union { __hip_bfloat16 b; unsigned short u; } cv;
  cv.b = __float2bfloat16(f);
  return cv.u;
}

static __device__ __forceinline__ void gload_lds16(const void* g, void* l) {
  __builtin_amdgcn_global_load_lds(
      (const __attribute__((address_space(1))) void*)g,
      (__attribute__((address_space(3))) void*)l, 16, 0, 0);
}

// ---------------- transpose tile: W [E][R][C] fp32 -> WT [E][C][R] bf16 -----
static __device__ void transpose_tile(const float* __restrict__ W,
                                      unsigned short* __restrict__ WT,
                                      int R, int C, int bx, int by, int e,
                                      float* smemf) {
  float (*tile)[65] = (float(*)[65])smemf;
  const int c0 = bx * 64, r0 = by * 64;
  const int lr = threadIdx.x >> 4;    // 0..15
  const int fc = threadIdx.x & 15;    // float4 column
  const float* Wp = W + ((size_t)e * R + r0) * C + c0;
#pragma unroll
  for (int i = 0; i < 4; ++i) {
    int r = lr + i * 16;
    float4 v = *(const float4*)(Wp + (size_t)r * C + fc * 4);
    tile[r][fc * 4 + 0] = v.x; tile[r][fc * 4 + 1] = v.y;
    tile[r][fc * 4 + 2] = v.z; tile[r][fc * 4 + 3] = v.w;
  }
  __syncthreads();
  unsigned short* Op = WT + ((size_t)e * C + c0) * R + r0;
  const int cc0 = threadIdx.x >> 3;   // 0..31
  const int rc = threadIdx.x & 7;     // 8-row source chunk
#pragma unroll
  for (int i = 0; i < 2; ++i) {
    int cc = cc0 + i * 32;
    short8 o;
#pragma unroll
    for (int j = 0; j < 8; ++j) o[j] = (short)f2bf(tile[rc * 8 + j][cc]);
    *(short8*)(Op + (size_t)cc * R + rc * 8) = o;   // 16B/lane, coalesced
  }
}

// 4 tiles per block (amortizes launch/fixed cost); barrier guards LDS reuse.
static __device__ void transpose_quad(const float* __restrict__ W,
                                      unsigned short* __restrict__ WT,
                                      int R, int C, int xtiles, int b,
                                      float* smemf) {
  for (int i = 0; i < 4; ++i) {
    if (i) __syncthreads();            // prev tile's LDS reads done
    int t = b * 4 + i;
    int e = t >> 9, rem = t & 511;
    transpose_tile(W, WT, R, C, rem & (xtiles - 1), rem / xtiles, e, smemf);
  }
}

// ---------------- router: x fp32 -> xb bf16 + probs + routes ----------------
// Stages WrL ONCE, then processes 4 token-groups (16 tokens) per block.
static __device__ void router_body4(const float* __restrict__ x,
                                    const float* __restrict__ Wr,
                                    const float* __restrict__ br,
                                    unsigned short* __restrict__ xb,
                                    float* __restrict__ probs_out,
                                    int* __restrict__ routes,
                                    int blk, float* smemf) {
  float (*WrL)[DIN] = (float(*)[DIN])smemf;   // [NEXP][DIN] = 32 KB
  const int tid = threadIdx.x;
  {
    const int r0 = tid * 4;
    float wlo[4][4], whi[4][4];
#pragma unroll
    for (int rr = 0; rr < 4; ++rr) {
      float4 v0 = *(const float4*)(Wr + (size_t)(r0 + rr) * NEXP);
      float4 v1 = *(const float4*)(Wr + (size_t)(r0 + rr) * NEXP + 4);
      wlo[rr][0] = v0.x; wlo[rr][1] = v0.y; wlo[rr][2] = v0.z; wlo[rr][3] = v0.w;
      whi[rr][0] = v1.x; whi[rr][1] = v1.y; whi[rr][2] = v1.z; whi[rr][3] = v1.w;
    }
#pragma unroll
    for (int e = 0; e < 4; ++e) {
      float4 o = { wlo[0][e], wlo[1][e], wlo[2][e], wlo[3][e] };
      *(float4*)&WrL[e][r0] = o;                 // lane stride 16B: no conflict
      float4 o2 = { whi[0][e], whi[1][e], whi[2][e], whi[3][e] };
      *(float4*)&WrL[e + 4][r0] = o2;
    }
  }
  __syncthreads();

  const int lane = tid & 63;
  for (int g = 0; g < 4; ++g) {
    const int n = blk * 16 + g * 4 + (tid >> 6);
    const float4* xr = (const float4*)(x + (size_t)n * DIN);
    ushort4* xo = (ushort4*)(xb + (size_t)n * DIN);
    float acc[NEXP];
#pragma unroll
    for (int e = 0; e < NEXP; ++e) acc[e] = 0.f;
#pragma unroll
    for (int j = 0; j < 4; ++j) {
      int idx = j * 64 + lane;          // coalesced: 64 consecutive float4
      float4 xv = xr[idx];
      ushort4 o = { f2bf(xv.x), f2bf(xv.y), f2bf(xv.z), f2bf(xv.w) };
      xo[idx] = o;
      int r0 = idx * 4;
#pragma unroll
      for (int e = 0; e < NEXP; ++e) {
        float4 wv = *(const float4*)&WrL[e][r0];
        acc[e] += xv.x * wv.x + xv.y * wv.y + xv.z * wv.z + xv.w * wv.w;
      }
    }
#pragma unroll
    for (int m = 1; m < 64; m <<= 1)
#pragma unroll
      for (int e = 0; e < NEXP; ++e) acc[e] += __shfl_xor(acc[e], m);

    if (lane == 0) {
      float lg[NEXP], p[NEXP];
      float mx = -1e30f;
#pragma unroll
      for (int e = 0; e < NEXP; ++e) { lg[e] = acc[e] + br[e]; mx = fmaxf(mx, lg[e]); }
      float s = 0.f;
#pragma unroll
      for (int e = 0; e < NEXP; ++e) { p[e] = expf(lg[e] - mx); s += p[e]; }
      float inv = 1.f / s;
      int best = 0; float bp = -1.f;
#pragma unroll
      for (int e = 0; e < NEXP; ++e) {
        p[e] *= inv;
        probs_out[(size_t)n * NEXP + e] = p[e];
        if (p[e] > bp) { bp = p[e]; best = e; }   // strict > tie-break
      }
      routes[n] = best;
    }
  }
}

// ============ prep1: W1-transpose | router (critical path for GEMM1) =======
__global__ __launch_bounds__(256) void prep1_kernel(
    const float* __restrict__ W1, unsigned short* __restrict__ w1t,
    const float* __restrict__ x, const float* __restrict__ Wr,
    const float* __restrict__ br, unsigned short* __restrict__ xb,
    float* __restrict__ probs_out, int* __restrict__ routes) {
  __shared__ float smemf[8192];   // 32 KB union
  const int bid = blockIdx.x;
  if (bid < T1BLK) {
    transpose_quad(W1, w1t, DIN, HID, 32, bid, smemf);  // W1: 32 x-tiles
  } else {
    router_body4(x, Wr, br, xb, probs_out, routes, bid - T1BLK, smemf);
  }
}

// ====== fused hist + scan + build + pad-fill (ONE single-block kernel) ======
__global__ __launch_bounds__(256) void hist_build_kernel(
    const int* __restrict__ routes, int* __restrict__ pad_off,
    int2* __restrict__ tile_table, float* __restrict__ counts_out,
    int* __restrict__ sorted) {
  __shared__ int rloc[NTOK];          // 32 KB
  __shared__ int cpre[256][NEXP];     // 8 KB
  __shared__ int tot[NEXP], pstart[NEXP], pend[NEXP];
  const int tid = threadIdx.x;
#pragma unroll
  for (int j = 0; j < 8; ++j)
    ((int4*)rloc)[tid + 256 * j] = ((const int4*)routes)[tid + 256 * j];
  __syncthreads();

  const int t0 = tid * 32;
  int cnt[NEXP];
#pragma unroll
  for (int e = 0; e < NEXP; ++e) cnt[e] = 0;
  for (int i = 0; i < 32; ++i) {
    int r = rloc[t0 + i];
#pragma unroll
    for (int e = 0; e < NEXP; ++e) cnt[e] += (r == e);
  }
#pragma unroll
  for (int e = 0; e < NEXP; ++e) cpre[tid][e] = cnt[e];
  __syncthreads();
  if (tid < NEXP) {                    // 8 threads: serial exclusive prefix
    int run = 0;
    for (int i = 0; i < 256; ++i) { int c = cpre[i][tid]; cpre[i][tid] = run; run += c; }
    tot[tid] = run;
  }
  __syncthreads();
  if (tid == 0) {
    int off = 0, t = 0;
    for (int e = 0; e < NEXP; ++e) {
      int c = tot[e];
      pad_off[e] = off;
      counts_out[e] = (float)c;
      int tiles = (c + BM - 1) / BM;
      pstart[e] = off + c;
      pend[e] = off + tiles * BM;
      for (int i = 0; i < tiles; ++i) { tile_table[t] = make_int2(e, off + i * BM); ++t; }
      off += tiles * BM;
    }
    for (; t < MAXT; ++t) tile_table[t] = make_int2(-1, 0);
  }
  __syncthreads();
  int pos[NEXP];
#pragma unroll
  for (int e = 0; e < NEXP; ++e) pos[e] = pad_off[e] + cpre[tid][e];
  for (int i = 0; i < 32; ++i) {
    int r = rloc[t0 + i];
#pragma unroll
    for (int e = 0; e < NEXP; ++e)     // compile-time index: pos stays in regs
      if (r == e) { sorted[pos[e]] = t0 + i; ++pos[e]; }
  }
#pragma unroll
  for (int e = 0; e < NEXP; ++e)
    for (int i = pstart[e] + tid; i < pend[e]; i += 256) sorted[i] = -1;
}

// ===== grouped GEMM body: m97 structure. 128x128 tile, BK=64, 4 waves, ======
// SINGLE-buffered 32KB LDS, two __syncthreads per K-step, compiler-managed
// waits; 3 blocks/CU. OCCUPANCY IS CLOSED BOTH WAYS: true VGPR use ~148/wave
// (84 reported + 64 acc). bound 5 -> collapse to 48 VGPR, acc in scratch, 7x
// slower (R17). bound 4 + frag-reuse diet -> half-spill (WRITE +26MB) AND
// serialized k-halves, MfmaUtil 21->16.5 (R20). (256,3) is the optimum.
// Swizzle (G4): chunk ^= row&7 on pre-swizzled gload source AND
// byte ^= (fr&7)<<4 on ds_read (row bases x16 => row&7 == fr&7) (rule #21).
// MODE 0: A = xb gathered, out = relu(acc+b1) -> bf16 hbuf[token][NDIM]
// MODE 1: A = hbuf gathered, out = acc+b2     -> fp32 out[token][NDIM]
template <int KDIM, int MODE, int NB>
static __device__ void gemm_body(
    short* lds, int bid,
    const unsigned short* __restrict__ A, const unsigned short* __restrict__ WT,
    const float* __restrict__ bias, const int* __restrict__ sorted,
    const int2* __restrict__ tile_table, void* __restrict__ Cout, int NDIM) {
  // T1 bijective XCD swizzle (nwg % 8 == 0)
  const int nwg = NB * MAXT;
  const int swz = (bid & 7) * (nwg >> 3) + (bid >> 3);
  const int2 tt = tile_table[swz / NB];
  if (tt.x < 0) return;
  const int expert = tt.x, mbase = tt.y;
  const int n0 = (swz % NB) * 128;
  const int tid = threadIdx.x, lane = tid & 63, w = tid >> 6;
  const int qm = w >> 1, qn = w & 1;
  const int fr = lane & 15, klo = lane >> 4;

  // ---- staging: 8 x 16B chunks per thread per K-tile (4 A + 4 B) ----
  const short* srcA[4];
  const short* srcB[4];
  int dstA[4], dstB[4];
#pragma unroll
  for (int i = 0; i < 4; ++i) {
    const int ch = i * 256 + tid;                       // 0..1023 (row-major)
    const int row = ch >> 3;                            // 128 rows x 8 chunks
    const int csw = ((ch & 7) ^ (row & 7)) * 8;         // inverse-swizzled source
    int tok = sorted[mbase + row];
    if (tok < 0) tok = 0;                               // pad: dropped at store
    srcA[i] = (const short*)A + (size_t)tok * KDIM + csw;
    srcB[i] = (const short*)WT + ((size_t)expert * NDIM + n0 + row) * KDIM + csw;
    dstA[i] = ch * 8;                                   // linear LDS dest
    dstB[i] = 8192 + ch * 8;
  }

  // ---- fragment ds_read offsets (shorts, swizzled) ----
  const int rsw = (fr & 7) << 4;            // row&7 == fr&7 (bases are x16)
  int aoff[4][2], boff[4][2];
#pragma unroll
  for (int i = 0; i < 4; ++i)
#pragma unroll
    for (int k = 0; k < 2; ++k) {
      int ba = (qm * 64 + i * 16 + fr) * 128 + k * 64 + klo * 16;
      aoff[i][k] = (ba ^ rsw) >> 1;
      int bb = (qn * 64 + i * 16 + fr) * 128 + k * 64 + klo * 16;
      boff[i][k] = ((bb ^ rsw) >> 1) + 8192;
    }

  f32x4 acc[4][4];
#pragma unroll
  for (int mi = 0; mi < 4; ++mi)
#pragma unroll
    for (int nj = 0; nj < 4; ++nj) acc[mi][nj] = (f32x4){0.f, 0.f, 0.f, 0.f};

  constexpr int NKT = KDIM / 64;
  for (int t = 0; t < NKT; ++t) {
    if (t) __syncthreads();               // prev tile's reads done
    const int ko = t * 64;
#pragma unroll
    for (int i = 0; i < 4; ++i) {
      gload_lds16(srcA[i] + ko, &lds[dstA[i]]);
      gload_lds16(srcB[i] + ko, &lds[dstB[i]]);
    }
    __syncthreads();                      // compiler drains vmcnt(0): tile ready
    short8 a[4][2], b[4][2];
#pragma unroll
    for (int i = 0; i < 4; ++i)
#pragma unroll
      for (int k = 0; k < 2; ++k) {
        a[i][k] = *(const short8*)&lds[aoff[i][k]];
        b[i][k] = *(const short8*)&lds[boff[i][k]];
      }
    __builtin_amdgcn_s_setprio(1);
#pragma unroll
    for (int mi = 0; mi < 4; ++mi)
#pragma unroll
      for (int nj = 0; nj < 4; ++nj)
#pragma unroll
        for (int k = 0; k < 2; ++k)
          acc[mi][nj] = __builtin_amdgcn_mfma_f32_16x16x32_bf16(
              a[mi][k], b[nj][k], acc[mi][nj], 0, 0, 0);
    __builtin_amdgcn_s_setprio(0);
  }

  // ---- epilogue: scatter rows to token-indexed buffer ----
  const int fq = lane >> 4;
#pragma unroll
  for (int mi = 0; mi < 4; ++mi) {
    const int rbase = mbase + qm * 64 + mi * 16 + fq * 4;
    int tok[4];
#pragma unroll
    for (int r = 0; r < 4; ++r) tok[r] = sorted[rbase + r];
#pragma unroll
    for (int nj = 0; nj < 4; ++nj) {
      const int col = n0 + qn * 64 + nj * 16 + fr;
      const float bv = bias[(size_t)expert * NDIM + col];
#pragma unroll
      for (int r = 0; r < 4; ++r) {
        if (tok[r] < 0) continue;           // pad row
        float v = acc[mi][nj][r] + bv;
        if (MODE == 0) {
          ((unsigned short*)Cout)[(size_t)tok[r] * NDIM + col] = f2bf(fmaxf(v, 0.f));
        } else {
          ((float*)Cout)[(size_t)tok[r] * NDIM + col] = v;
        }
      }
    }
  }
}

// ===== kernel B: GEMM1 blocks first, then W2-transpose blocks (single-tile) =
__global__ __launch_bounds__(256, 3) void gemm1_t2_kernel(
    const unsigned short* __restrict__ xb, const unsigned short* __restrict__ w1t,
    const float* __restrict__ b1, const int* __restrict__ sorted,
    const int2* __restrict__ tile_table, unsigned short* __restrict__ hbuf,
    const float* __restrict__ W2, unsigned short* __restrict__ w2t) {
  __shared__ short lds[16384];   // 32 KB
  const int bid = blockIdx.x;
  if (bid < G1BLK) {
    gemm_body<DIN, 0, HID / 128>(lds, bid, xb, w1t, b1, sorted, tile_table,
                                 (void*)hbuf, HID);
  } else {
    int b = bid - G1BLK;          // W2: R=HID(32 tiles), C=OUTD(16 tiles)
    int e = b >> 9, rem = b & 511;
    transpose_tile(W2, w2t, HID, OUTD, rem & 15, rem >> 4, e, (float*)lds);
  }
}

template <int KDIM, int MODE, int NB>
__global__ __launch_bounds__(256, 3) void gemm_moe(
    const unsigned short* __restrict__ A, const unsigned short* __restrict__ WT,
    const float* __restrict__ bias, const int* __restrict__ sorted,
    const int2* __restrict__ tile_table, void* __restrict__ Cout, int NDIM) {
  __shared__ short lds[16384];   // 32 KB
  gemm_body<KDIM, MODE, NB>(lds, blockIdx.x, A, WT, bias, sorted, tile_table,
                            Cout, NDIM);
}

extern "C" void kernel_launch(void* const* d_in, const int* in_sizes, int n_in,
                              void* d_out, int out_size, void* d_ws, size_t ws_size,
                              hipStream_t stream) {
  const float* x  = (const float*)d_in[0];
  const float* Wr = (const float*)d_in[1];
  const float* br = (const float*)d_in[2];
  const float* W1 = (const float*)d_in[3];
  const float* b1 = (const float*)d_in[4];
  const float* W2 = (const float*)d_in[5];
  const float* b2 = (const float*)d_in[6];

  float* out_y      = (float*)d_out;                      // [N,O]
  float* out_probs  = out_y + (size_t)NTOK * OUTD;        // [N,E]
  float* out_counts = out_probs + (size_t)NTOK * NEXP;    // [E]

  char* ws = (char*)d_ws;
  unsigned short* xb   = (unsigned short*)(ws);                                  // 16 MB
  unsigned short* w1t  = (unsigned short*)(ws + 16777216ULL);                    // 32 MB
  unsigned short* w2t  = (unsigned short*)(ws + 50331648ULL);                    // 32 MB
  unsigned short* hbuf = (unsigned short*)(ws + 83886080ULL);                    // 32 MB (token-indexed)
  char* p = ws + 117440512ULL;
  int* routes   = (int*)p; p += 32768;
  int* sorted   = (int*)p; p += (NTOK + NEXP * BM) * 4;
  int* pad_off  = (int*)p; p += 256;
  int2* tt      = (int2*)p;

  prep1_kernel<<<T1BLK + RTBLK, 256, 0, stream>>>(
      W1, w1t, x, Wr, br, xb, out_probs, routes);
  hist_build_kernel<<<1, 256, 0, stream>>>(routes, pad_off, tt, out_counts,
                                           sorted);
  gemm1_t2_kernel<<<G1BLK + T2BLK, 256, 0, stream>>>(
      xb, w1t, b1, sorted, tt, hbuf, W2, w2t);
  gemm_moe<HID, 1, OUTD / 128><<<(OUTD / 128) * MAXT, 256, 0, stream>>>(
      hbuf, w2t, b2, sorted, tt, out_y, OUTD);
}

// Round 22
// 161.641 us; speedup vs baseline: 1.1701x; 1.0192x over previous
//
#include <hip/hip_runtime.h>
#include <hip/hip_bf16.h>

#define NTOK 8192
#define DIN  1024
#define HID  2048
#define OUTD 1024
#define NEXP 8
#define BM 128
#define MAXT (NTOK / BM + NEXP)   // 72 M-tiles max

#define T1BLK 1024                // W1 transpose blocks (4 tiles each): 4096/4
#define RTBLK 512                 // router blocks (4 groups each): 2048/4
#define T2BLK 4096                // W2 transpose blocks (1 tile each)
#define G1BLK ((HID / 128) * MAXT)   // 1152 GEMM1 blocks (div by 8)

typedef short short8 __attribute__((ext_vector_type(8)));
typedef float f32x4 __attribute__((ext_vector_type(4)));

static __device__ __forceinline__ unsigned short f2bf(float f) {
  union { __hip_bfloat16 b; unsigned short u; } cv;
  cv.b = __float2bfloat16(f);
  return cv.u;
}

static __device__ __forceinline__ void gload_lds16(const void* g, void* l) {
  __builtin_amdgcn_global_load_lds(
      (const __attribute__((address_space(1))) void*)g,
      (__attribute__((address_space(3))) void*)l, 16, 0, 0);
}

// ---------------- transpose tile: W [E][R][C] fp32 -> WT [E][C][R] bf16 -----
static __device__ void transpose_tile(const float* __restrict__ W,
                                      unsigned short* __restrict__ WT,
                                      int R, int C, int bx, int by, int e,
                                      float* smemf) {
  float (*tile)[65] = (float(*)[65])smemf;
  const int c0 = bx * 64, r0 = by * 64;
  const int lr = threadIdx.x >> 4;    // 0..15
  const int fc = threadIdx.x & 15;    // float4 column
  const float* Wp = W + ((size_t)e * R + r0) * C + c0;
#pragma unroll
  for (int i = 0; i < 4; ++i) {
    int r = lr + i * 16;
    float4 v = *(const float4*)(Wp + (size_t)r * C + fc * 4);
    tile[r][fc * 4 + 0] = v.x; tile[r][fc * 4 + 1] = v.y;
    tile[r][fc * 4 + 2] = v.z; tile[r][fc * 4 + 3] = v.w;
  }
  __syncthreads();
  unsigned short* Op = WT + ((size_t)e * C + c0) * R + r0;
  const int cc0 = threadIdx.x >> 3;   // 0..31
  const int rc = threadIdx.x & 7;     // 8-row source chunk
#pragma unroll
  for (int i = 0; i < 2; ++i) {
    int cc = cc0 + i * 32;
    short8 o;
#pragma unroll
    for (int j = 0; j < 8; ++j) o[j] = (short)f2bf(tile[rc * 8 + j][cc]);
    *(short8*)(Op + (size_t)cc * R + rc * 8) = o;   // 16B/lane, coalesced
  }
}

// 4 tiles per block (amortizes launch/fixed cost); barrier guards LDS reuse.
static __device__ void transpose_quad(const float* __restrict__ W,
                                      unsigned short* __restrict__ WT,
                                      int R, int C, int xtiles, int b,
                                      float* smemf) {
  for (int i = 0; i < 4; ++i) {
    if (i) __syncthreads();            // prev tile's LDS reads done
    int t = b * 4 + i;
    int e = t >> 9, rem = t & 511;
    transpose_tile(W, WT, R, C, rem & (xtiles - 1), rem / xtiles, e, smemf);
  }
}

// ---------------- router: x fp32 -> xb bf16 + probs + routes ----------------
// Stages WrL ONCE, then processes 4 token-groups (16 tokens) per block.
static __device__ void router_body4(const float* __restrict__ x,
                                    const float* __restrict__ Wr,
                                    const float* __restrict__ br,
                                    unsigned short* __restrict__ xb,
                                    float* __restrict__ probs_out,
                                    int* __restrict__ routes,
                                    int blk, float* smemf) {
  float (*WrL)[DIN] = (float(*)[DIN])smemf;   // [NEXP][DIN] = 32 KB
  const int tid = threadIdx.x;
  {
    const int r0 = tid * 4;
    float wlo[4][4], whi[4][4];
#pragma unroll
    for (int rr = 0; rr < 4; ++rr) {
      float4 v0 = *(const float4*)(Wr + (size_t)(r0 + rr) * NEXP);
      float4 v1 = *(const float4*)(Wr + (size_t)(r0 + rr) * NEXP + 4);
      wlo[rr][0] = v0.x; wlo[rr][1] = v0.y; wlo[rr][2] = v0.z; wlo[rr][3] = v0.w;
      whi[rr][0] = v1.x; whi[rr][1] = v1.y; whi[rr][2] = v1.z; whi[rr][3] = v1.w;
    }
#pragma unroll
    for (int e = 0; e < 4; ++e) {
      float4 o = { wlo[0][e], wlo[1][e], wlo[2][e], wlo[3][e] };
      *(float4*)&WrL[e][r0] = o;                 // lane stride 16B: no conflict
      float4 o2 = { whi[0][e], whi[1][e], whi[2][e], whi[3][e] };
      *(float4*)&WrL[e + 4][r0] = o2;
    }
  }
  __syncthreads();

  const int lane = tid & 63;
  for (int g = 0; g < 4; ++g) {
    const int n = blk * 16 + g * 4 + (tid >> 6);
    const float4* xr = (const float4*)(x + (size_t)n * DIN);
    ushort4* xo = (ushort4*)(xb + (size_t)n * DIN);
    float acc[NEXP];
#pragma unroll
    for (int e = 0; e < NEXP; ++e) acc[e] = 0.f;
#pragma unroll
    for (int j = 0; j < 4; ++j) {
      int idx = j * 64 + lane;          // coalesced: 64 consecutive float4
      float4 xv = xr[idx];
      ushort4 o = { f2bf(xv.x), f2bf(xv.y), f2bf(xv.z), f2bf(xv.w) };
      xo[idx] = o;
      int r0 = idx * 4;
#pragma unroll
      for (int e = 0; e < NEXP; ++e) {
        float4 wv = *(const float4*)&WrL[e][r0];
        acc[e] += xv.x * wv.x + xv.y * wv.y + xv.z * wv.z + xv.w * wv.w;
      }
    }
#pragma unroll
    for (int m = 1; m < 64; m <<= 1)
#pragma unroll
      for (int e = 0; e < NEXP; ++e) acc[e] += __shfl_xor(acc[e], m);

    if (lane == 0) {
      float lg[NEXP], p[NEXP];
      float mx = -1e30f;
#pragma unroll
      for (int e = 0; e < NEXP; ++e) { lg[e] = acc[e] + br[e]; mx = fmaxf(mx, lg[e]); }
      float s = 0.f;
#pragma unroll
      for (int e = 0; e < NEXP; ++e) { p[e] = expf(lg[e] - mx); s += p[e]; }
      float inv = 1.f / s;
      int best = 0; float bp = -1.f;
#pragma unroll
      for (int e = 0; e < NEXP; ++e) {
        p[e] *= inv;
        probs_out[(size_t)n * NEXP + e] = p[e];
        if (p[e] > bp) { bp = p[e]; best = e; }   // strict > tie-break
      }
      routes[n] = best;
    }
  }
}

// ============ prep1: W1-transpose | router (critical path for GEMM1) =======
__global__ __launch_bounds__(256) void prep1_kernel(
    const float* __restrict__ W1, unsigned short* __restrict__ w1t,
    const float* __restrict__ x, const float* __restrict__ Wr,
    const float* __restrict__ br, unsigned short* __restrict__ xb,
    float* __restrict__ probs_out, int* __restrict__ routes) {
  __shared__ float smemf[8192];   // 32 KB union
  const int bid = blockIdx.x;
  if (bid < T1BLK) {
    transpose_quad(W1, w1t, DIN, HID, 32, bid, smemf);  // W1: 32 x-tiles
  } else {
    router_body4(x, Wr, br, xb, probs_out, routes, bid - T1BLK, smemf);
  }
}

// ====== fused hist + scan + build + pad-fill (ONE single-block kernel) ======
// R22: serial 8-thread prefix (256 dependent LDS iterations ~ 10us of whole-
// machine idle) replaced by two-level PARALLEL scan: per-wave inclusive scan
// via __shfl_up (6 steps x 8 experts, compile-time-indexed regs, rule #20),
// wave totals in LDS, cross-wave offset <= 3 adds. Placement loop unchanged.
__global__ __launch_bounds__(256) void hist_build_kernel(
    const int* __restrict__ routes, int* __restrict__ pad_off,
    int2* __restrict__ tile_table, float* __restrict__ counts_out,
    int* __restrict__ sorted) {
  __shared__ int rloc[NTOK];          // 32 KB
  __shared__ int wtot[4][NEXP];
  __shared__ int spad[NEXP], pstart[NEXP], pend[NEXP];
  const int tid = threadIdx.x;
  const int lane = tid & 63, w = tid >> 6;
#pragma unroll
  for (int j = 0; j < 8; ++j)
    ((int4*)rloc)[tid + 256 * j] = ((const int4*)routes)[tid + 256 * j];
  __syncthreads();

  const int t0 = tid * 32;
  int cnt[NEXP];
#pragma unroll
  for (int e = 0; e < NEXP; ++e) cnt[e] = 0;
  for (int i = 0; i < 32; ++i) {
    int r = rloc[t0 + i];
#pragma unroll
    for (int e = 0; e < NEXP; ++e) cnt[e] += (r == e);
  }
  // ---- wave-level inclusive scan (registers only) ----
  int inc[NEXP];
#pragma unroll
  for (int e = 0; e < NEXP; ++e) inc[e] = cnt[e];
#pragma unroll
  for (int d = 1; d < 64; d <<= 1)
#pragma unroll
    for (int e = 0; e < NEXP; ++e) {
      int v = __shfl_up(inc[e], d);
      if (lane >= d) inc[e] += v;
    }
  if (lane == 63)
#pragma unroll
    for (int e = 0; e < NEXP; ++e) wtot[w][e] = inc[e];
  __syncthreads();

  // ---- cross-wave offset + totals (each thread, small) ----
  int exc[NEXP];
#pragma unroll
  for (int e = 0; e < NEXP; ++e) {
    int off = 0;
#pragma unroll
    for (int ww = 0; ww < 4; ++ww) off += (ww < w) ? wtot[ww][e] : 0;
    exc[e] = off + inc[e] - cnt[e];     // exclusive prefix for this thread
  }

  if (tid == 0) {
    int off = 0, t = 0;
    for (int e = 0; e < NEXP; ++e) {
      int c = wtot[0][e] + wtot[1][e] + wtot[2][e] + wtot[3][e];
      pad_off[e] = off;
      spad[e] = off;
      counts_out[e] = (float)c;
      int tiles = (c + BM - 1) / BM;
      pstart[e] = off + c;
      pend[e] = off + tiles * BM;
      for (int i = 0; i < tiles; ++i) { tile_table[t] = make_int2(e, off + i * BM); ++t; }
      off += tiles * BM;
    }
    for (; t < MAXT; ++t) tile_table[t] = make_int2(-1, 0);
  }
  __syncthreads();
  int pos[NEXP];
#pragma unroll
  for (int e = 0; e < NEXP; ++e) pos[e] = spad[e] + exc[e];
  for (int i = 0; i < 32; ++i) {
    int r = rloc[t0 + i];
#pragma unroll
    for (int e = 0; e < NEXP; ++e)     // compile-time index: pos stays in regs
      if (r == e) { sorted[pos[e]] = t0 + i; ++pos[e]; }
  }
#pragma unroll
  for (int e = 0; e < NEXP; ++e)
    for (int i = pstart[e] + tid; i < pend[e]; i += 256) sorted[i] = -1;
}

// ===== grouped GEMM body: m97 structure. 128x128 tile, BK=64, 4 waves, ======
// SINGLE-buffered 32KB LDS, two __syncthreads per K-step, compiler-managed
// waits; 3 blocks/CU. OCCUPANCY IS CLOSED BOTH WAYS: true VGPR use ~148/wave
// (84 reported + 64 acc). bound 5 -> collapse to 48 VGPR, acc in scratch, 7x
// slower (R17). bound 4 + frag-reuse diet -> half-spill (WRITE +26MB) AND
// serialized k-halves, MfmaUtil 21->16.5 (R20). (256,3) is the optimum.
// Swizzle (G4): chunk ^= row&7 on pre-swizzled gload source AND
// byte ^= (fr&7)<<4 on ds_read (row bases x16 => row&7 == fr&7) (rule #21).
// MODE 0: A = xb gathered, out = relu(acc+b1) -> bf16 hbuf[token][NDIM]
// MODE 1: A = hbuf gathered, out = acc+b2     -> fp32 out[token][NDIM]
template <int KDIM, int MODE, int NB>
static __device__ void gemm_body(
    short* lds, int bid,
    const unsigned short* __restrict__ A, const unsigned short* __restrict__ WT,
    const float* __restrict__ bias, const int* __restrict__ sorted,
    const int2* __restrict__ tile_table, void* __restrict__ Cout, int NDIM) {
  // T1 bijective XCD swizzle (nwg % 8 == 0)
  const int nwg = NB * MAXT;
  const int swz = (bid & 7) * (nwg >> 3) + (bid >> 3);
  const int2 tt = tile_table[swz / NB];
  if (tt.x < 0) return;
  const int expert = tt.x, mbase = tt.y;
  const int n0 = (swz % NB) * 128;
  const int tid = threadIdx.x, lane = tid & 63, w = tid >> 6;
  const int qm = w >> 1, qn = w & 1;
  const int fr = lane & 15, klo = lane >> 4;

  // ---- staging: 8 x 16B chunks per thread per K-tile (4 A + 4 B) ----
  const short* srcA[4];
  const short* srcB[4];
  int dstA[4], dstB[4];
#pragma unroll
  for (int i = 0; i < 4; ++i) {
    const int ch = i * 256 + tid;                       // 0..1023 (row-major)
    const int row = ch >> 3;                            // 128 rows x 8 chunks
    const int csw = ((ch & 7) ^ (row & 7)) * 8;         // inverse-swizzled source
    int tok = sorted[mbase + row];
    if (tok < 0) tok = 0;                               // pad: dropped at store
    srcA[i] = (const short*)A + (size_t)tok * KDIM + csw;
    srcB[i] = (const short*)WT + ((size_t)expert * NDIM + n0 + row) * KDIM + csw;
    dstA[i] = ch * 8;                                   // linear LDS dest
    dstB[i] = 8192 + ch * 8;
  }

  // ---- fragment ds_read offsets (shorts, swizzled) ----
  const int rsw = (fr & 7) << 4;            // row&7 == fr&7 (bases are x16)
  int aoff[4][2], boff[4][2];
#pragma unroll
  for (int i = 0; i < 4; ++i)
#pragma unroll
    for (int k = 0; k < 2; ++k) {
      int ba = (qm * 64 + i * 16 + fr) * 128 + k * 64 + klo * 16;
      aoff[i][k] = (ba ^ rsw) >> 1;
      int bb = (qn * 64 + i * 16 + fr) * 128 + k * 64 + klo * 16;
      boff[i][k] = ((bb ^ rsw) >> 1) + 8192;
    }

  f32x4 acc[4][4];
#pragma unroll
  for (int mi = 0; mi < 4; ++mi)
#pragma unroll
    for (int nj = 0; nj < 4; ++nj) acc[mi][nj] = (f32x4){0.f, 0.f, 0.f, 0.f};

  constexpr int NKT = KDIM / 64;
  for (int t = 0; t < NKT; ++t) {
    if (t) __syncthreads();               // prev tile's reads done
    const int ko = t * 64;
#pragma unroll
    for (int i = 0; i < 4; ++i) {
      gload_lds16(srcA[i] + ko, &lds[dstA[i]]);
      gload_lds16(srcB[i] + ko, &lds[dstB[i]]);
    }
    __syncthreads();                      // compiler drains vmcnt(0): tile ready
    short8 a[4][2], b[4][2];
#pragma unroll
    for (int i = 0; i < 4; ++i)
#pragma unroll
      for (int k = 0; k < 2; ++k) {
        a[i][k] = *(const short8*)&lds[aoff[i][k]];
        b[i][k] = *(const short8*)&lds[boff[i][k]];
      }
    __builtin_amdgcn_s_setprio(1);
#pragma unroll
    for (int mi = 0; mi < 4; ++mi)
#pragma unroll
      for (int nj = 0; nj < 4; ++nj)
#pragma unroll
        for (int k = 0; k < 2; ++k)
          acc[mi][nj] = __builtin_amdgcn_mfma_f32_16x16x32_bf16(
              a[mi][k], b[nj][k], acc[mi][nj], 0, 0, 0);
    __builtin_amdgcn_s_setprio(0);
  }

  // ---- epilogue: scatter rows to token-indexed buffer ----
  const int fq = lane >> 4;
#pragma unroll
  for (int mi = 0; mi < 4; ++mi) {
    const int rbase = mbase + qm * 64 + mi * 16 + fq * 4;
    int tok[4];
#pragma unroll
    for (int r = 0; r < 4; ++r) tok[r] = sorted[rbase + r];
#pragma unroll
    for (int nj = 0; nj < 4; ++nj) {
      const int col = n0 + qn * 64 + nj * 16 + fr;
      const float bv = bias[(size_t)expert * NDIM + col];
#pragma unroll
      for (int r = 0; r < 4; ++r) {
        if (tok[r] < 0) continue;           // pad row
        float v = acc[mi][nj][r] + bv;
        if (MODE == 0) {
          ((unsigned short*)Cout)[(size_t)tok[r] * NDIM + col] = f2bf(fmaxf(v, 0.f));
        } else {
          ((float*)Cout)[(size_t)tok[r] * NDIM + col] = v;
        }
      }
    }
  }
}

// ===== kernel B: GEMM1 blocks first, then W2-transpose blocks (single-tile) =
__global__ __launch_bounds__(256, 3) void gemm1_t2_kernel(
    const unsigned short* __restrict__ xb, const unsigned short* __restrict__ w1t,
    const float* __restrict__ b1, const int* __restrict__ sorted,
    const int2* __restrict__ tile_table, unsigned short* __restrict__ hbuf,
    const float* __restrict__ W2, unsigned short* __restrict__ w2t) {
  __shared__ short lds[16384];   // 32 KB
  const int bid = blockIdx.x;
  if (bid < G1BLK) {
    gemm_body<DIN, 0, HID / 128>(lds, bid, xb, w1t, b1, sorted, tile_table,
                                 (void*)hbuf, HID);
  } else {
    int b = bid - G1BLK;          // W2: R=HID(32 tiles), C=OUTD(16 tiles)
    int e = b >> 9, rem = b & 511;
    transpose_tile(W2, w2t, HID, OUTD, rem & 15, rem >> 4, e, (float*)lds);
  }
}

template <int KDIM, int MODE, int NB>
__global__ __launch_bounds__(256, 3) void gemm_moe(
    const unsigned short* __restrict__ A, const unsigned short* __restrict__ WT,
    const float* __restrict__ bias, const int* __restrict__ sorted,
    const int2* __restrict__ tile_table, void* __restrict__ Cout, int NDIM) {
  __shared__ short lds[16384];   // 32 KB
  gemm_body<KDIM, MODE, NB>(lds, blockIdx.x, A, WT, bias, sorted, tile_table,
                            Cout, NDIM);
}

extern "C" void kernel_launch(void* const* d_in, const int* in_sizes, int n_in,
                              void* d_out, int out_size, void* d_ws, size_t ws_size,
                              hipStream_t stream) {
  const float* x  = (const float*)d_in[0];
  const float* Wr = (const float*)d_in[1];
  const float* br = (const float*)d_in[2];
  const float* W1 = (const float*)d_in[3];
  const float* b1 = (const float*)d_in[4];
  const float* W2 = (const float*)d_in[5];
  const float* b2 = (const float*)d_in[6];

  float* out_y      = (float*)d_out;                      // [N,O]
  float* out_probs  = out_y + (size_t)NTOK * OUTD;        // [N,E]
  float* out_counts = out_probs + (size_t)NTOK * NEXP;    // [E]

  char* ws = (char*)d_ws;
  unsigned short* xb   = (unsigned short*)(ws);                                  // 16 MB
  unsigned short* w1t  = (unsigned short*)(ws + 16777216ULL);                    // 32 MB
  unsigned short* w2t  = (unsigned short*)(ws + 50331648ULL);                    // 32 MB
  unsigned short* hbuf = (unsigned short*)(ws + 83886080ULL);                    // 32 MB (token-indexed)
  char* p = ws + 117440512ULL;
  int* routes   = (int*)p; p += 32768;
  int* sorted   = (int*)p; p += (NTOK + NEXP * BM) * 4;
  int* pad_off  = (int*)p; p += 256;
  int2* tt      = (int2*)p;

  prep1_kernel<<<T1BLK + RTBLK, 256, 0, stream>>>(
      W1, w1t, x, Wr, br, xb, out_probs, routes);
  hist_build_kernel<<<1, 256, 0, stream>>>(routes, pad_off, tt, out_counts,
                                           sorted);
  gemm1_t2_kernel<<<G1BLK + T2BLK, 256, 0, stream>>>(
      xb, w1t, b1, sorted, tt, hbuf, W2, w2t);
  gemm_moe<HID, 1, OUTD / 128><<<(OUTD / 128) * MAXT, 256, 0, stream>>>(
      hbuf, w2t, b2, sorted, tt, out_y, OUTD);
}